// Round 12
// baseline (138.044 us; speedup 1.0000x reference)
//
#include <hip/hip_runtime.h>

#define NBATCH 4
#define DDIM   256
#define NN     4096
#define MM     4096
#define NCHUNK 8          // m-chunks (split-K across workgroups)
#define MCHUNK 512        // m per chunk
#define MTILE  64         // m per LDS tile (8 tiles/chunk)
#define LOG2E  1.44269504088896340736f

using half8   = __attribute__((ext_vector_type(8))) _Float16;
using floatx4 = __attribute__((ext_vector_type(4))) float;

// Fragment-ordered fp16 layout (per batch): half8 at ((blk*8 + ds)*4 + quad)*16 + l15
// covers point p = blk*16 + l15, dims d = ds*32 + quad*8 .. +7.  A-frag reads and
// DMA staging are both lane-contiguous -> conflict-free LDS + coalesced global.

// ---------- prep: emb[b][d][n] fp32 -> fragment-ordered fp16; fused yy + Vt ----------
__global__ __launch_bounds__(256) void k_prep(const float* __restrict__ src_emb,
                                              const float* __restrict__ tgt_emb,
                                              const float* __restrict__ tgt,
                                              _Float16* __restrict__ Qf,
                                              _Float16* __restrict__ Kf,
                                              float* __restrict__ yyS,
                                              float4* __restrict__ Vt) {
    __shared__ float psum[4][64];
    int i = blockIdx.x;                            // 512 = xcd(8) x j(64)
    int xcd = i & 7, j = i >> 3;
    int b = xcd >> 1, nhalf = xcd & 1;             // matches flash's XCD mapping
    int tensor = j & 1, sub = j >> 1;              // sub 0..31
    int n0 = nhalf * 2048 + sub * 64;
    const float* in = tensor ? tgt_emb : src_emb;
    _Float16* outp  = tensor ? Kf : Qf;
    const float scale = tensor ? 1.0f : 2.0f * LOG2E;   // fold 2*log2e into Q
    int t = threadIdx.x, w = t >> 6, ln = t & 63;
    const float* ib = in + (size_t)b * DDIM * NN + n0 + ln;
    _Float16* ob = outp + (size_t)b * NN * 32 * 8;      // batch-b fragment space
    int blk = (n0 + ln) >> 4, l15 = ln & 15;
    float ss = 0.f;
#pragma unroll
    for (int h = 0; h < 2; h++) {                  // wave w covers ds in {w, w+4}
        int ds = w + h * 4;
#pragma unroll
        for (int oct = 0; oct < 4; oct++) {
            half8 v;
#pragma unroll
            for (int k = 0; k < 8; k++) {
                float f = ib[(size_t)(ds * 32 + oct * 8 + k) * NN];  // 256B/wave coalesced
                ss = fmaf(f, f, ss);
                v[k] = (_Float16)(f * scale);
            }
            *(half8*)(ob + ((((size_t)blk * 8 + ds) * 4 + oct) * 16 + l15) * 8) = v;
        }
    }
    if (tensor) psum[w][ln] = ss;
    __syncthreads();
    if (tensor) {
        if (t < 64) {
            float s = psum[0][t] + psum[1][t] + psum[2][t] + psum[3][t];
            yyS[b * MM + n0 + t] = s * (-LOG2E);   // pre-negated, exp2-domain
        } else if (t < 128) {
            int m = n0 + (t - 64);
            const float* tp = tgt + (size_t)b * 3 * MM + m;
            Vt[(size_t)b * MM + m] = make_float4(tp[0], tp[MM], tp[2 * MM], 1.0f);
        }
    }
}

// ---------- flash: R8 skeleton + pair-batched softmax (2 updates/tile not 4) ----------
__global__ __launch_bounds__(256, 2) void k_flash(const _Float16* __restrict__ Qf,
                                                  const _Float16* __restrict__ Kf,
                                                  const float* __restrict__ yyS,
                                                  const float4* __restrict__ Vt,
                                                  float4* __restrict__ Opart,
                                                  float* __restrict__ Mpart) {
    __shared__ __align__(16) _Float16 Kt[2][MTILE * DDIM];   // 2 x 32 KB, fragment order
    __shared__ floatx4 vtt[MCHUNK];                          // 8 KB {v0,v1,v2,1}
    __shared__ floatx4 yyt[MCHUNK / 4];                      // 2 KB

    int i = blockIdx.x, t = threadIdx.x;           // grid 512 = xcd(8) x j(64)
    int xcd = i & 7, j = i >> 3;
    int b = xcd >> 1, nhalf = xcd & 1;             // per-XCD K slice L2-resident
    int chunk = j & 7, ntile = nhalf * 8 + (j >> 3);

    int wave = t >> 6, lane = t & 63, quad = lane >> 4, l15 = lane & 15;
    int m0 = chunk * MCHUNK;
    int mblk0 = m0 >> 4;                           // chunk's first 16-point blk

    // linear DMA: tile mt = 32 KB contiguous in fragment space; pure memcpy to LDS
    const char* kfb = (const char*)(Kf + (size_t)b * NN * DDIM);
    auto stage = [&](int mt) {
        const char* gb = kfb + (size_t)(mblk0 + mt * 4) * 8192 + wave * 8192;
        char* lb = (char*)&Kt[mt & 1][0] + wave * 8192;
#pragma unroll
        for (int it = 0; it < 8; it++) {
            __builtin_amdgcn_global_load_lds(
                (const __attribute__((address_space(1))) uint32_t*)(const void*)
                    (gb + it * 1024 + lane * 16),
                (__attribute__((address_space(3))) uint32_t*)(void*)
                    (lb + it * 1024),
                16, 0, 0);
        }
    };

    stage(0);                                      // K-tile 0 in flight first

    // whole-chunk V + yy staged ONCE (no global loads inside the K-loop)
    {
        const float4* vb = Vt + (size_t)b * MM + m0;
        for (int r = t; r < MCHUNK; r += 256) {
            float4 g = vb[r];
            vtt[r] = (floatx4){g.x, g.y, g.z, g.w};
        }
        const floatx4* yb = (const floatx4*)(yyS + (size_t)b * MM + m0);
        if (t < MCHUNK / 4) yyt[t] = yb[t];
    }

    // persistent Q fragments: 64n x 256d per wave (128 VGPRs), fragment-order loads
    int nblk0 = ntile * 16 + wave * 4;
    const half8* qp = (const half8*)Qf + (size_t)b * NN * 32;
    half8 qf[4][8];
#pragma unroll
    for (int nb = 0; nb < 4; nb++)
#pragma unroll
        for (int ds = 0; ds < 8; ds++)
            qf[nb][ds] = qp[(((size_t)(nblk0 + nb) * 8 + ds) * 4 + quad) * 16 + l15];

    const floatx4 z4 = {0.f, 0.f, 0.f, 0.f};
    floatx4 o[4] = {z4, z4, z4, z4};               // per-quad partial {o0,o1,o2,denom}
    float mr[4];
#pragma unroll
    for (int nb = 0; nb < 4; nb++) mr[nb] = -__builtin_inff();

    for (int mt = 0; mt < MCHUNK / MTILE; mt++) {
        __syncthreads();                           // drains DMA(mt) (issued one tile ago)
        if (mt + 1 < MCHUNK / MTILE) stage(mt + 1);     // prefetch flies over this tile

        const char* Kb = (const char*)&Kt[mt & 1][0];
#pragma unroll
        for (int h = 0; h < 2; h++) {              // 32-m pair: blocks 2h, 2h+1
            const char* rb0 = Kb + (2 * h) * 8192 + lane * 16;
            const char* rb1 = rb0 + 8192;
            half8 a0[8], a1[8];
#pragma unroll
            for (int ds = 0; ds < 8; ds++) { a0[ds] = *(const half8*)(rb0 + ds * 1024);
                                             a1[ds] = *(const half8*)(rb1 + ds * 1024); }

            floatx4 acc[4][2];
#pragma unroll
            for (int nb = 0; nb < 4; nb++) { acc[nb][0] = z4; acc[nb][1] = z4; }
#pragma unroll
            for (int ds = 0; ds < 8; ds++)
#pragma unroll
                for (int nb = 0; nb < 4; nb++) {
                    acc[nb][0] = __builtin_amdgcn_mfma_f32_16x16x32_f16(a0[ds], qf[nb][ds], acc[nb][0], 0, 0, 0);
                    acc[nb][1] = __builtin_amdgcn_mfma_f32_16x16x32_f16(a1[ds], qf[nb][ds], acc[nb][1], 0, 0, 0);
                }

            // yy + V for this quad's 8 m's (quad-broadcast LDS reads)
            int mq = mt * 16 + 8 * h;
            floatx4 yv0 = yyt[mq + quad];
            floatx4 yv1 = yyt[mq + 4 + quad];
            int mv = mt * MTILE + 32 * h + quad * 4;
            floatx4 vr0[4], vr1[4];
#pragma unroll
            for (int r = 0; r < 4; r++) { vr0[r] = vtt[mv + r]; vr1[r] = vtt[mv + 16 + r]; }

            // ONE softmax update per nb per 32 m (pair-batched)
#pragma unroll
            for (int nb = 0; nb < 4; nb++) {
                acc[nb][0] = acc[nb][0] + yv0;
                acc[nb][1] = acc[nb][1] + yv1;
                floatx4 mx = __builtin_elementwise_max(acc[nb][0], acc[nb][1]);
                float tm = fmaxf(fmaxf(mx[0], mx[1]), fmaxf(mx[2], mx[3]));
                float mn = fmaxf(mr[nb], tm);
                float al = __builtin_amdgcn_exp2f(mr[nb] - mn);
                mr[nb] = mn;
                o[nb] = o[nb] * al;
#pragma unroll
                for (int r = 0; r < 4; r++) {
                    float p0 = __builtin_amdgcn_exp2f(acc[nb][0][r] - mn);
                    o[nb] = o[nb] + p0 * vr0[r];
                    float p1 = __builtin_amdgcn_exp2f(acc[nb][1][r] - mn);
                    o[nb] = o[nb] + p1 * vr1[r];
                }
            }
        }
    }

    // merge the 4 per-quad partial softmaxes (once per kernel)
#pragma unroll
    for (int nb = 0; nb < 4; nb++) {
        float mq = mr[nb];
        float ma = fmaxf(mq, __shfl_xor(mq, 16, 64));
        ma = fmaxf(ma, __shfl_xor(ma, 32, 64));
        float wgt = __builtin_amdgcn_exp2f(mq - ma);
        floatx4 ow = o[nb] * wgt;
#pragma unroll
        for (int c = 0; c < 4; c++) {
            float v = ow[c];
            v += __shfl_xor(v, 16, 64);
            v += __shfl_xor(v, 32, 64);
            ow[c] = v;
        }
        if (quad == 0) {
            int n = (nblk0 + nb) * 16 + l15;
            size_t idx = (size_t)(chunk * NBATCH + b) * NN + n;
            Opart[idx] = make_float4(ow[0], ow[1], ow[2], ow[3]);
            Mpart[idx] = ma;
        }
    }
}

// ---------- combine the 8 m-chunk partials per (b,n) ----------
__global__ __launch_bounds__(128) void k_combine(const float4* __restrict__ Opart,
                                                 const float* __restrict__ Mpart,
                                                 float* __restrict__ out) {
    int idx = blockIdx.x * 128 + threadIdx.x;      // b*NN + n
    int b = idx >> 12, n = idx & (NN - 1);
    float mstar = -__builtin_inff();
#pragma unroll
    for (int j = 0; j < NCHUNK; j++)
        mstar = fmaxf(mstar, Mpart[(size_t)(j * NBATCH + b) * NN + n]);
    float o0 = 0.f, o1 = 0.f, o2 = 0.f, l = 0.f;
#pragma unroll
    for (int j = 0; j < NCHUNK; j++) {
        size_t id = (size_t)(j * NBATCH + b) * NN + n;
        float w = __builtin_amdgcn_exp2f(Mpart[id] - mstar);
        float4 P = Opart[id];
        o0 = fmaf(w, P.x, o0); o1 = fmaf(w, P.y, o1);
        o2 = fmaf(w, P.z, o2); l  = fmaf(w, P.w, l);
    }
    out[(size_t)(b * 3 + 0) * NN + n] = o0 / l;
    out[(size_t)(b * 3 + 1) * NN + n] = o1 / l;
    out[(size_t)(b * 3 + 2) * NN + n] = o2 / l;
}

extern "C" void kernel_launch(void* const* d_in, const int* in_sizes, int n_in,
                              void* d_out, int out_size, void* d_ws, size_t ws_size,
                              hipStream_t stream) {
    const float* tgt     = (const float*)d_in[1];
    const float* src_emb = (const float*)d_in[2];
    const float* tgt_emb = (const float*)d_in[3];
    float* out = (float*)d_out;

    char* ws = (char*)d_ws;
    // ws: Qf 8.39M | Kf 8.39M | yyS 64K | Vt 256K | Opart 2M | Mpart 512K  (~19.7 MB)
    _Float16* Qf  = (_Float16*)(ws);
    _Float16* Kf  = (_Float16*)(ws + 8388608);
    float*    yyS = (float*)   (ws + 16777216);
    float4*   Vt  = (float4*)  (ws + 16842752);
    float4*   Op  = (float4*)  (ws + 17104896);
    float*    Mp  = (float*)   (ws + 19202048);

    hipLaunchKernelGGL(k_prep,    dim3(512), dim3(256), 0, stream,
                       src_emb, tgt_emb, tgt, Qf, Kf, yyS, Vt);
    hipLaunchKernelGGL(k_flash,   dim3(512), dim3(256), 0, stream, Qf, Kf, yyS, Vt, Op, Mp);
    hipLaunchKernelGGL(k_combine, dim3(128), dim3(128), 0, stream, Op, Mp, out);
}

// Round 13
// 125.906 us; speedup vs baseline: 1.0964x; 1.0964x over previous
//
#include <hip/hip_runtime.h>

#define NBATCH 4
#define DDIM   256
#define NN     4096
#define MM     4096
#define NCHUNK 8          // m-chunks (split-K across workgroups)
#define MCHUNK 512        // m per chunk
#define MTILE  64         // m per LDS tile (8 tiles/chunk)
#define LOG2E  1.44269504088896340736f

using half8   = __attribute__((ext_vector_type(8))) _Float16;
using floatx4 = __attribute__((ext_vector_type(4))) float;

// Fragment-ordered fp16 layout (per batch): half8 at ((blk*8 + ds)*4 + quad)*16 + l15
// covers point p = blk*16 + l15, dims d = ds*32 + quad*8 .. +7.  A-frag reads and
// DMA staging are both lane-contiguous -> conflict-free LDS + coalesced global.

// ---------- prep: emb[b][d][n] fp32 -> fragment-ordered fp16; fused yy + Vt ----------
__global__ __launch_bounds__(256) void k_prep(const float* __restrict__ src_emb,
                                              const float* __restrict__ tgt_emb,
                                              const float* __restrict__ tgt,
                                              _Float16* __restrict__ Qf,
                                              _Float16* __restrict__ Kf,
                                              float* __restrict__ yyS,
                                              float4* __restrict__ Vt) {
    __shared__ float psum[4][64];
    int i = blockIdx.x;                            // 512 = xcd(8) x j(64)
    int xcd = i & 7, j = i >> 3;
    int b = xcd >> 1, nhalf = xcd & 1;             // matches flash's XCD mapping
    int tensor = j & 1, sub = j >> 1;              // sub 0..31
    int n0 = nhalf * 2048 + sub * 64;
    const float* in = tensor ? tgt_emb : src_emb;
    _Float16* outp  = tensor ? Kf : Qf;
    const float scale = tensor ? 1.0f : 2.0f * LOG2E;   // fold 2*log2e into Q
    int t = threadIdx.x, w = t >> 6, ln = t & 63;
    const float* ib = in + (size_t)b * DDIM * NN + n0 + ln;
    _Float16* ob = outp + (size_t)b * NN * 32 * 8;      // batch-b fragment space
    int blk = (n0 + ln) >> 4, l15 = ln & 15;
    float ss = 0.f;
#pragma unroll
    for (int h = 0; h < 2; h++) {                  // wave w covers ds in {w, w+4}
        int ds = w + h * 4;
#pragma unroll
        for (int oct = 0; oct < 4; oct++) {
            half8 v;
#pragma unroll
            for (int k = 0; k < 8; k++) {
                float f = ib[(size_t)(ds * 32 + oct * 8 + k) * NN];  // 256B/wave coalesced
                ss = fmaf(f, f, ss);
                v[k] = (_Float16)(f * scale);
            }
            *(half8*)(ob + ((((size_t)blk * 8 + ds) * 4 + oct) * 16 + l15) * 8) = v;
        }
    }
    if (tensor) psum[w][ln] = ss;
    __syncthreads();
    if (tensor) {
        if (t < 64) {
            float s = psum[0][t] + psum[1][t] + psum[2][t] + psum[3][t];
            yyS[b * MM + n0 + t] = s * (-LOG2E);   // pre-negated, exp2-domain
        } else if (t < 128) {
            int m = n0 + (t - 64);
            const float* tp = tgt + (size_t)b * 3 * MM + m;
            Vt[(size_t)b * MM + m] = make_float4(tp[0], tp[MM], tp[2 * MM], 1.0f);
        }
    }
}

// ---------- flash: linear-DMA dbuf K (fragment order), 1 barrier/tile ----------
__global__ __launch_bounds__(256, 2) void k_flash(const _Float16* __restrict__ Qf,
                                                  const _Float16* __restrict__ Kf,
                                                  const float* __restrict__ yyS,
                                                  const float4* __restrict__ Vt,
                                                  float4* __restrict__ Opart,
                                                  float* __restrict__ Mpart) {
    __shared__ __align__(16) _Float16 Kt[2][MTILE * DDIM];   // 2 x 32 KB, fragment order
    __shared__ floatx4 vtt[MCHUNK];                          // 8 KB {v0,v1,v2,1}
    __shared__ floatx4 yyt[MCHUNK / 4];                      // 2 KB

    int i = blockIdx.x, t = threadIdx.x;           // grid 512 = xcd(8) x j(64)
    int xcd = i & 7, j = i >> 3;
    int b = xcd >> 1, nhalf = xcd & 1;             // per-XCD K slice L2-resident
    int chunk = j & 7, ntile = nhalf * 8 + (j >> 3);

    int wave = t >> 6, lane = t & 63, quad = lane >> 4, l15 = lane & 15;
    int m0 = chunk * MCHUNK;
    int mblk0 = m0 >> 4;                           // chunk's first 16-point blk

    // linear DMA: tile mt = 32 KB contiguous in fragment space; pure memcpy to LDS
    const char* kfb = (const char*)(Kf + (size_t)b * NN * DDIM);
    auto stage = [&](int mt) {
        const char* gb = kfb + (size_t)(mblk0 + mt * 4) * 8192 + wave * 8192;
        char* lb = (char*)&Kt[mt & 1][0] + wave * 8192;
#pragma unroll
        for (int it = 0; it < 8; it++) {
            __builtin_amdgcn_global_load_lds(
                (const __attribute__((address_space(1))) uint32_t*)(const void*)
                    (gb + it * 1024 + lane * 16),
                (__attribute__((address_space(3))) uint32_t*)(void*)
                    (lb + it * 1024),
                16, 0, 0);
        }
    };

    stage(0);                                      // K-tile 0 in flight first

    // whole-chunk V + yy staged ONCE (no global loads inside the K-loop)
    {
        const float4* vb = Vt + (size_t)b * MM + m0;
        for (int r = t; r < MCHUNK; r += 256) {
            float4 g = vb[r];
            vtt[r] = (floatx4){g.x, g.y, g.z, g.w};
        }
        const floatx4* yb = (const floatx4*)(yyS + (size_t)b * MM + m0);
        if (t < MCHUNK / 4) yyt[t] = yb[t];
    }

    // persistent Q fragments: 64n x 256d per wave (128 VGPRs), fragment-order loads
    int nblk0 = ntile * 16 + wave * 4;
    const half8* qp = (const half8*)Qf + (size_t)b * NN * 32;
    half8 qf[4][8];
#pragma unroll
    for (int nb = 0; nb < 4; nb++)
#pragma unroll
        for (int ds = 0; ds < 8; ds++)
            qf[nb][ds] = qp[(((size_t)(nblk0 + nb) * 8 + ds) * 4 + quad) * 16 + l15];

    const floatx4 z4 = {0.f, 0.f, 0.f, 0.f};
    floatx4 o[4] = {z4, z4, z4, z4};               // per-quad partial {o0,o1,o2,denom}
    float mr[4];
#pragma unroll
    for (int nb = 0; nb < 4; nb++) mr[nb] = -__builtin_inff();

    for (int mt = 0; mt < MCHUNK / MTILE; mt++) {
        __syncthreads();                           // drains DMA(mt) (issued one tile ago)
        if (mt + 1 < MCHUNK / MTILE) stage(mt + 1);     // prefetch flies over this tile

        const char* Kb = (const char*)&Kt[mt & 1][0];
#pragma unroll
        for (int mb = 0; mb < 4; mb++) {           // 16-m block; quad owns m=..+quad*4+r
            // A-frags: base + lane*16 -> lane-contiguous ds_read_b128 (conflict-free)
            const char* rb = Kb + mb * 8192 + lane * 16;
            half8 a[8];
#pragma unroll
            for (int ds = 0; ds < 8; ds++) a[ds] = *(const half8*)(rb + ds * 1024);

            floatx4 acc[4] = {z4, z4, z4, z4};
#pragma unroll
            for (int ds = 0; ds < 8; ds++)
#pragma unroll
                for (int nb = 0; nb < 4; nb++)
                    acc[nb] = __builtin_amdgcn_mfma_f32_16x16x32_f16(a[ds], qf[nb][ds], acc[nb], 0, 0, 0);

            // per-quad online softmax (exp2 domain) + PV
            floatx4 yv = yyt[mt * 16 + mb * 4 + quad];
            floatx4 vr[4];
#pragma unroll
            for (int r = 0; r < 4; r++) vr[r] = vtt[mt * MTILE + mb * 16 + quad * 4 + r];
#pragma unroll
            for (int nb = 0; nb < 4; nb++) {
                acc[nb] = acc[nb] + yv;
                float tm = fmaxf(fmaxf(acc[nb][0], acc[nb][1]), fmaxf(acc[nb][2], acc[nb][3]));
                float mn = fmaxf(mr[nb], tm);
                float al = __builtin_amdgcn_exp2f(mr[nb] - mn);
                mr[nb] = mn;
                o[nb] = o[nb] * al;
#pragma unroll
                for (int r = 0; r < 4; r++) {
                    float p = __builtin_amdgcn_exp2f(acc[nb][r] - mn);
                    o[nb] = o[nb] + p * vr[r];
                }
            }
        }
    }

    // merge the 4 per-quad partial softmaxes (once per kernel)
#pragma unroll
    for (int nb = 0; nb < 4; nb++) {
        float mq = mr[nb];
        float ma = fmaxf(mq, __shfl_xor(mq, 16, 64));
        ma = fmaxf(ma, __shfl_xor(ma, 32, 64));
        float wgt = __builtin_amdgcn_exp2f(mq - ma);
        floatx4 ow = o[nb] * wgt;
#pragma unroll
        for (int c = 0; c < 4; c++) {
            float v = ow[c];
            v += __shfl_xor(v, 16, 64);
            v += __shfl_xor(v, 32, 64);
            ow[c] = v;
        }
        if (quad == 0) {
            int n = (nblk0 + nb) * 16 + l15;
            size_t idx = (size_t)(chunk * NBATCH + b) * NN + n;
            Opart[idx] = make_float4(ow[0], ow[1], ow[2], ow[3]);
            Mpart[idx] = ma;
        }
    }
}

// ---------- combine the 8 m-chunk partials per (b,n) ----------
__global__ __launch_bounds__(128) void k_combine(const float4* __restrict__ Opart,
                                                 const float* __restrict__ Mpart,
                                                 float* __restrict__ out) {
    int idx = blockIdx.x * 128 + threadIdx.x;      // b*NN + n
    int b = idx >> 12, n = idx & (NN - 1);
    float mstar = -__builtin_inff();
#pragma unroll
    for (int j = 0; j < NCHUNK; j++)
        mstar = fmaxf(mstar, Mpart[(size_t)(j * NBATCH + b) * NN + n]);
    float o0 = 0.f, o1 = 0.f, o2 = 0.f, l = 0.f;
#pragma unroll
    for (int j = 0; j < NCHUNK; j++) {
        size_t id = (size_t)(j * NBATCH + b) * NN + n;
        float w = __builtin_amdgcn_exp2f(Mpart[id] - mstar);
        float4 P = Opart[id];
        o0 = fmaf(w, P.x, o0); o1 = fmaf(w, P.y, o1);
        o2 = fmaf(w, P.z, o2); l  = fmaf(w, P.w, l);
    }
    out[(size_t)(b * 3 + 0) * NN + n] = o0 / l;
    out[(size_t)(b * 3 + 1) * NN + n] = o1 / l;
    out[(size_t)(b * 3 + 2) * NN + n] = o2 / l;
}

extern "C" void kernel_launch(void* const* d_in, const int* in_sizes, int n_in,
                              void* d_out, int out_size, void* d_ws, size_t ws_size,
                              hipStream_t stream) {
    const float* tgt     = (const float*)d_in[1];
    const float* src_emb = (const float*)d_in[2];
    const float* tgt_emb = (const float*)d_in[3];
    float* out = (float*)d_out;

    char* ws = (char*)d_ws;
    // ws: Qf 8.39M | Kf 8.39M | yyS 64K | Vt 256K | Opart 2M | Mpart 512K  (~19.7 MB)
    _Float16* Qf  = (_Float16*)(ws);
    _Float16* Kf  = (_Float16*)(ws + 8388608);
    float*    yyS = (float*)   (ws + 16777216);
    float4*   Vt  = (float4*)  (ws + 16842752);
    float4*   Op  = (float4*)  (ws + 17104896);
    float*    Mp  = (float*)   (ws + 19202048);

    hipLaunchKernelGGL(k_prep,    dim3(512), dim3(256), 0, stream,
                       src_emb, tgt_emb, tgt, Qf, Kf, yyS, Vt);
    hipLaunchKernelGGL(k_flash,   dim3(512), dim3(256), 0, stream, Qf, Kf, yyS, Vt, Op, Mp);
    hipLaunchKernelGGL(k_combine, dim3(128), dim3(128), 0, stream, Op, Mp, out);
}